// Round 4
// baseline (1096.525 us; speedup 1.0000x reference)
//
#include <hip/hip_runtime.h>
#include <hip/hip_bf16.h>
#include <math.h>

// COSGATEncoder: N=50000, E=1280000, D=64, HEADS=1.
// Runtime-detected dtypes: x/weights bf16-vs-f32, edge_index int32-vs-int64.
// Output written in the same dtype as x. Workspace ~33 MB.

constexpr int D = 64;
constexpr float NEG_SLOPE = 0.2f;
constexpr float EPS_COS = 1e-8f;
constexpr float EPS_SM = 1e-16f;

__device__ __forceinline__ float wred_sum(float v) {
#pragma unroll
  for (int off = 32; off > 0; off >>= 1) v += __shfl_xor(v, off, 64);
  return v;
}
__device__ __forceinline__ float elu1(float x) { return x > 0.f ? x : expf(x) - 1.f; }
__device__ __forceinline__ float sane(float v) {
  return (v == v && fabsf(v) < 1e30f) ? v : 0.f;
}

// dtype-flexible load/store: f32 flag chooses float vs bf16 view
__device__ __forceinline__ float ldv(const void* p, size_t i, int f32) {
  return f32 ? ((const float*)p)[i]
             : __bfloat162float(((const __hip_bfloat16*)p)[i]);
}
__device__ __forceinline__ void stv(void* p, size_t i, int f32, float v) {
  if (f32) ((float*)p)[i] = v;
  else ((__hip_bfloat16*)p)[i] = __float2bfloat16(v);
}

// flags[0]: 1 if x/weights are f32, 0 if bf16.  flags[1]: 1 if edge_index int64.
__global__ void k_detect(const unsigned short* __restrict__ xu,
                         const int* __restrict__ ei, int* __restrict__ flags) {
  if (blockIdx.x == 0 && threadIdx.x == 0) {
    int plaus = 0;
    for (int i = 0; i < 128; ++i) {
      unsigned int f = ((unsigned int)xu[i]) << 16;
      float v = __uint_as_float(f);
      float a = fabsf(v);
      if (a > 1e-4f && a < 100.f) plaus++;
    }
    flags[0] = (plaus >= 120) ? 0 : 1;  // all-plausible bf16 decode => truly bf16
    int nz = 0;
    for (int i = 1; i < 128; i += 2) nz |= ei[i];
    flags[1] = (nz == 0) ? 1 : 0;  // hi-words all zero => int64
  }
}

__device__ __forceinline__ int ld_src(const int* ei, int E, int e, int wide, int N) {
  int v = wide ? ei[2 * e] : ei[e];
  return min(max(v, 0), N - 1);
}
__device__ __forceinline__ int ld_dst(const int* ei, int E, int e, int wide, int N) {
  int v = wide ? ei[2 * E + 2 * e] : ei[E + e];
  return min(max(v, 0), N - 1);
}

// ---------------- CSR build ----------------
__global__ void k_count(const int* __restrict__ ei, int E, int N,
                        const int* __restrict__ flags, int* __restrict__ counts) {
  int e = blockIdx.x * blockDim.x + threadIdx.x;
  if (e < E) atomicAdd(&counts[ld_dst(ei, E, e, flags[1], N)], 1);
}

__global__ void __launch_bounds__(1024) k_scan(const int* __restrict__ counts,
                                               int* __restrict__ row_ptr,
                                               int* __restrict__ wptr, int n) {
  __shared__ int sums[1024];
  const int t = threadIdx.x;
  const int chunk = (n + 1023) >> 10;
  const int lo = t * chunk;
  const int hi = min(lo + chunk, n);
  int s = 0;
  for (int i = lo; i < hi; ++i) s += counts[i];
  sums[t] = s;
  __syncthreads();
  for (int off = 1; off < 1024; off <<= 1) {
    int v = (t >= off) ? sums[t - off] : 0;
    __syncthreads();
    sums[t] += v;
    __syncthreads();
  }
  int offset = (t == 0) ? 0 : sums[t - 1];
  for (int i = lo; i < hi; ++i) {
    row_ptr[i] = offset;
    wptr[i] = offset;
    offset += counts[i];
  }
  if (t == 1023) row_ptr[n] = sums[1023];
}

__global__ void k_fill(const int* __restrict__ ei, const void* __restrict__ w,
                       int E, int N, const int* __restrict__ flags,
                       int* __restrict__ wptr, int* __restrict__ csr_src,
                       _Float16* __restrict__ gbuf) {
  int e = blockIdx.x * blockDim.x + threadIdx.x;
  if (e < E) {
    int wide = flags[1], f32 = flags[0];
    int src = ld_src(ei, E, e, wide, N);
    int dst = ld_dst(ei, E, e, wide, N);
    int pos = atomicAdd(&wptr[dst], 1);
    pos = min(max(pos, 0), E - 1);
    csr_src[pos] = src;
    float wv = ldv(w, e, f32);
    float wcl = fminf(wv, 4.f);
    float g = fminf(fmaxf(1.f - 0.25f * wcl, 0.f), 1.f);
    gbuf[pos] = (_Float16)g;
  }
}

// ---------------- per-layer node prep ----------------
__global__ void __launch_bounds__(256) k_prep(const void* __restrict__ xin,
                                              const void* __restrict__ W,
                                              const void* __restrict__ att,
                                              const int* __restrict__ flags,
                                              __hip_bfloat16* __restrict__ fhat,
                                              float* __restrict__ Hmat,
                                              float* __restrict__ a_l, float* __restrict__ a_r,
                                              int N) {
  const int lane = threadIdx.x & 63;
  const int wid = (blockIdx.x * 256 + threadIdx.x) >> 6;
  if (wid >= N) return;
  const int f32 = flags[0];
  float f = ldv(xin, (size_t)wid * D + lane, f32);
  float n2 = wred_sum(f * f);
  float nrm = fmaxf(sqrtf(n2), EPS_COS);
  fhat[(size_t)wid * D + lane] = __float2bfloat16(f / nrm);
  float Hc = 0.f;
#pragma unroll 8
  for (int k = 0; k < D; ++k) {
    float fk = __shfl(f, k, 64);
    Hc += fk * ldv(W, k * D + lane, f32);
  }
  Hmat[(size_t)wid * D + lane] = Hc;
  float al = wred_sum(Hc * ldv(att, lane, f32));
  float ar = wred_sum(Hc * ldv(att, D + lane, f32));
  if (lane == 0) {
    a_l[wid] = al;
    a_r[wid] = ar;
  }
}

// ---------------- edge kernel: wave per dst node ----------------
__global__ void __launch_bounds__(256) k_edge(const int* __restrict__ row_ptr,
                                              const int* __restrict__ csr_src,
                                              const _Float16* __restrict__ gbuf,
                                              _Float16* __restrict__ lbuf,
                                              _Float16* __restrict__ cbuf,
                                              const __hip_bfloat16* __restrict__ fhat,
                                              const float* __restrict__ Hmat,
                                              const float* __restrict__ a_l,
                                              const float* __restrict__ a_r,
                                              const void* __restrict__ beta,
                                              const void* __restrict__ bias,
                                              const void* __restrict__ x,
                                              const void* __restrict__ rW1,
                                              const void* __restrict__ rb1,
                                              const void* __restrict__ rW2,
                                              const void* __restrict__ rb2,
                                              const int* __restrict__ flags,
                                              void* __restrict__ out,
                                              int N, int E, int layer) {
  const int lane = threadIdx.x & 63;
  const int wid = (blockIdx.x * 256 + threadIdx.x) >> 6;
  const bool act = wid < N;
  const int f32 = flags[0];
  int s = 0, e = 0;
  float fn = 0.f, aln = 0.f;
  if (act) {
    s = min(max(row_ptr[wid], 0), E);
    e = min(max(row_ptr[wid + 1], s), E);
    fn = __bfloat162float(fhat[(size_t)wid * D + lane]);
    aln = a_l[wid];
  }
  // phase 1: logits + cosine per edge; exact segment maxes
  float m1 = -1e30f, m2 = -1e30f;
  for (int j = s; j < e; ++j) {
    int src = min(max(csr_src[j], 0), N - 1);
    float d = wred_sum(fn * __bfloat162float(fhat[(size_t)src * D + lane]));
    float l = aln + a_r[src];
    l = (l >= 0.f) ? l : NEG_SLOPE * l;
    m1 = fmaxf(m1, l);
    m2 = fmaxf(m2, d);
    if (lane == 0) {
      lbuf[j] = (_Float16)l;
      cbuf[j] = (_Float16)d;
    }
  }
  __syncthreads();
  // phase 2: softmax denominators (lane-parallel)
  float ps1 = 0.f, ps2 = 0.f;
  for (int j = s + lane; j < e; j += 64) {
    ps1 += expf((float)lbuf[j] - m1);
    ps2 += expf((float)cbuf[j] - m2);
  }
  float rs1 = 1.f / (wred_sum(ps1) + EPS_SM);
  float rs2 = 1.f / (wred_sum(ps2) + EPS_SM);
  float bb = 1.f / (1.f + expf(-ldv(beta, 0, f32)));
  float ob = 1.f - bb;
  // phase 3: fused weight, 3rd softmax (fixed shift; t in [0,1]), message accum
  float acc = 0.f, s3 = 0.f;
  for (int j = s; j < e; ++j) {
    int src = min(max(csr_src[j], 0), N - 1);
    float el = expf((float)lbuf[j] - m1);
    float ec = expf((float)cbuf[j] - m2);
    float t = (ob * el * rs1 + bb * ec * rs2) * (float)gbuf[j];
    float p = expf(t - 1.f);
    s3 += p;
    acc += p * Hmat[(size_t)src * D + lane];
  }
  if (act) {
    float v = acc / (s3 + EPS_SM) + ldv(bias, lane, f32);
    v = elu1(v);  // elu inside _cosgat
    if (layer == 0) {
      v = elu1(v);  // inter-layer elu
    } else {
      // fused residual MLP: relu(x@rW1+rb1)@rW2+rb2
      float xv = ldv(x, (size_t)wid * D + lane, f32);
      float a1 = ldv(rb1, lane, f32);
#pragma unroll 8
      for (int k = 0; k < D; ++k) {
        float xk = __shfl(xv, k, 64);
        a1 += xk * ldv(rW1, k * D + lane, f32);
      }
      float tr = fmaxf(a1, 0.f);
      float a2 = ldv(rb2, lane, f32);
#pragma unroll 8
      for (int k = 0; k < D; ++k) {
        float tk = __shfl(tr, k, 64);
        a2 += tk * ldv(rW2, k * D + lane, f32);
      }
      v += a2;
    }
    stv(out, (size_t)wid * D + lane, f32, sane(v));
  }
}

extern "C" void kernel_launch(void* const* d_in, const int* in_sizes, int n_in,
                              void* d_out, int out_size, void* d_ws, size_t ws_size,
                              hipStream_t stream) {
  const void* x = d_in[0];
  const int* ei = (const int*)d_in[1];
  const void* w = d_in[2];
  const void* W0 = d_in[3];
  const void* att0 = d_in[4];
  const void* beta0 = d_in[5];
  const void* b0 = d_in[6];
  const void* W1 = d_in[7];
  const void* att1 = d_in[8];
  const void* beta1 = d_in[9];
  const void* b1 = d_in[10];
  const void* rW1 = d_in[11];
  const void* rb1 = d_in[12];
  const void* rW2 = d_in[13];
  const void* rb2 = d_in[14];

  const int N = in_sizes[0] / D;
  const int E = in_sizes[2];

  char* base = (char*)d_ws;
  size_t off = 0;
  auto alloc = [&](size_t bytes) -> void* {
    void* p = base + off;
    off += (bytes + 255) & ~(size_t)255;
    return p;
  };
  // Total ~33.0 MB
  int* flags = (int*)alloc(256);
  int* counts = (int*)alloc((size_t)N * 4);
  int* wptr = (int*)alloc((size_t)N * 4);
  int* row_ptr = (int*)alloc((size_t)(N + 1) * 4);
  int* csr_src = (int*)alloc((size_t)E * 4);
  _Float16* gbuf = (_Float16*)alloc((size_t)E * 2);
  _Float16* cbuf = (_Float16*)alloc((size_t)E * 2);
  _Float16* lbuf = (_Float16*)alloc((size_t)E * 2);
  __hip_bfloat16* fhat = (__hip_bfloat16*)alloc((size_t)N * D * 2);
  float* Hmat = (float*)alloc((size_t)N * D * 4);
  float* a_l = (float*)alloc((size_t)N * 4);
  float* a_r = (float*)alloc((size_t)N * 4);
  (void)ws_size;

  const int eb = (E + 255) / 256;
  const int nb = (N + 3) / 4;

  hipMemsetAsync(counts, 0, (size_t)N * 4, stream);
  k_detect<<<1, 64, 0, stream>>>((const unsigned short*)x, ei, flags);
  k_count<<<eb, 256, 0, stream>>>(ei, E, N, flags, counts);
  k_scan<<<1, 1024, 0, stream>>>(counts, row_ptr, wptr, N);
  k_fill<<<eb, 256, 0, stream>>>(ei, w, E, N, flags, wptr, csr_src, gbuf);

  // layer 0: stage elu(elu(.)) into d_out (in detected dtype)
  k_prep<<<nb, 256, 0, stream>>>(x, W0, att0, flags, fhat, Hmat, a_l, a_r, N);
  k_edge<<<nb, 256, 0, stream>>>(row_ptr, csr_src, gbuf, lbuf, cbuf, fhat, Hmat, a_l, a_r,
                                 beta0, b0, x, rW1, rb1, rW2, rb2, flags, d_out, N, E, 0);
  // layer 1: read d_out, overwrite with final = cosgat + residual
  k_prep<<<nb, 256, 0, stream>>>(d_out, W1, att1, flags, fhat, Hmat, a_l, a_r, N);
  k_edge<<<nb, 256, 0, stream>>>(row_ptr, csr_src, gbuf, lbuf, cbuf, fhat, Hmat, a_l, a_r,
                                 beta1, b1, x, rW1, rb1, rW2, rb2, flags, d_out, N, E, 1);
}

// Round 5
// 695.790 us; speedup vs baseline: 1.5759x; 1.5759x over previous
//
#include <hip/hip_runtime.h>
#include <hip/hip_bf16.h>
#include <math.h>

// COSGATEncoder: N=50000, E=1280000, D=64, HEADS=1. f32 in/out (runtime-detected,
// bf16 fallback), edge_index int64 (runtime-detected, int32 fallback).
// R5: k_edge VALU diet — __expf, 4-edge/16-lane phase-1 dots, broadcast phase-3.

constexpr int D = 64;
constexpr float NEG_SLOPE = 0.2f;
constexpr float EPS_COS = 1e-8f;
constexpr float EPS_SM = 1e-16f;

__device__ __forceinline__ float wred_sum(float v) {
#pragma unroll
  for (int off = 32; off > 0; off >>= 1) v += __shfl_xor(v, off, 64);
  return v;
}
__device__ __forceinline__ float elu1(float x) { return x > 0.f ? x : __expf(x) - 1.f; }
__device__ __forceinline__ float sane(float v) {
  return (v == v && fabsf(v) < 1e30f) ? v : 0.f;
}
__device__ __forceinline__ float ldv(const void* p, size_t i, int f32) {
  return f32 ? ((const float*)p)[i]
             : __bfloat162float(((const __hip_bfloat16*)p)[i]);
}
__device__ __forceinline__ void stv(void* p, size_t i, int f32, float v) {
  if (f32) ((float*)p)[i] = v;
  else ((__hip_bfloat16*)p)[i] = __float2bfloat16(v);
}
__device__ __forceinline__ float b2f(unsigned short u) {
  unsigned int w = ((unsigned int)u) << 16;
  return __uint_as_float(w);
}

// flags[0]=1 if x/weights f32; flags[1]=1 if edge_index int64
__global__ void k_detect(const unsigned short* __restrict__ xu,
                         const int* __restrict__ ei, int* __restrict__ flags) {
  const int t = threadIdx.x;  // 64
  float v = b2f(xu[t]);
  float a = fabsf(v);
  unsigned long long m = __ballot(a > 1e-4f && a < 100.f);
  unsigned long long m2 = __ballot(ei[2 * t + 1] != 0);
  if (t == 0) {
    flags[0] = (__popcll(m) >= 60) ? 0 : 1;
    flags[1] = (m2 == 0ull) ? 1 : 0;
  }
}

__device__ __forceinline__ int ld_src(const int* ei, int E, int e, int wide, int N) {
  int v = wide ? ei[2 * e] : ei[e];
  return min(max(v, 0), N - 1);
}
__device__ __forceinline__ int ld_dst(const int* ei, int E, int e, int wide, int N) {
  int v = wide ? ei[2 * E + 2 * e] : ei[E + e];
  return min(max(v, 0), N - 1);
}

// ---------------- CSR build ----------------
__global__ void k_count(const int* __restrict__ ei, int E, int N,
                        const int* __restrict__ flags, int* __restrict__ counts) {
  int e = blockIdx.x * blockDim.x + threadIdx.x;
  if (e < E) atomicAdd(&counts[ld_dst(ei, E, e, flags[1], N)], 1);
}

// 3-pass multiblock exclusive scan of counts -> row_ptr (+wptr), row_ptr[n]=E
__global__ void k_scanA(const int* __restrict__ counts, int* __restrict__ row_ptr,
                        int* __restrict__ partials, int n) {
  __shared__ int sm[256];
  const int t = threadIdx.x;
  const int i = blockIdx.x * 256 + t;
  int v = (i < n) ? counts[i] : 0;
  sm[t] = v;
  __syncthreads();
  for (int off = 1; off < 256; off <<= 1) {
    int u = (t >= off) ? sm[t - off] : 0;
    __syncthreads();
    sm[t] += u;
    __syncthreads();
  }
  if (i < n) row_ptr[i] = sm[t] - v;  // exclusive within block
  if (t == 255) partials[blockIdx.x] = sm[255];
}
__global__ void __launch_bounds__(1024) k_scanB(int* __restrict__ partials,
                                                int* __restrict__ row_ptr,
                                                int nb, int n) {
  __shared__ int sm[1024];
  const int t = threadIdx.x;
  int v = (t < nb) ? partials[t] : 0;
  sm[t] = v;
  __syncthreads();
  for (int off = 1; off < 1024; off <<= 1) {
    int u = (t >= off) ? sm[t - off] : 0;
    __syncthreads();
    sm[t] += u;
    __syncthreads();
  }
  if (t < nb) partials[t] = sm[t] - v;  // exclusive across blocks
  if (t == nb - 1) row_ptr[n] = sm[t];  // total
}
__global__ void k_scanC(int* __restrict__ row_ptr, int* __restrict__ wptr,
                        const int* __restrict__ partials, int n) {
  const int i = blockIdx.x * 256 + threadIdx.x;
  if (i < n) {
    int r = row_ptr[i] + partials[blockIdx.x];
    row_ptr[i] = r;
    wptr[i] = r;
  }
}

__global__ void k_fill(const int* __restrict__ ei, const void* __restrict__ w,
                       int E, int N, const int* __restrict__ flags,
                       int* __restrict__ wptr, int* __restrict__ csr_src,
                       _Float16* __restrict__ gbuf) {
  int e = blockIdx.x * blockDim.x + threadIdx.x;
  if (e < E) {
    int wide = flags[1], f32 = flags[0];
    int src = ld_src(ei, E, e, wide, N);
    int dst = ld_dst(ei, E, e, wide, N);
    int pos = atomicAdd(&wptr[dst], 1);
    pos = min(max(pos, 0), E - 1);
    csr_src[pos] = src;
    float wv = ldv(w, e, f32);
    float g = fminf(fmaxf(1.f - 0.25f * fminf(wv, 4.f), 0.f), 1.f);
    gbuf[pos] = (_Float16)g;
  }
}

// ---------------- per-layer node prep ----------------
__global__ void __launch_bounds__(256) k_prep(const void* __restrict__ xin,
                                              const void* __restrict__ W,
                                              const void* __restrict__ att,
                                              const int* __restrict__ flags,
                                              __hip_bfloat16* __restrict__ fhat,
                                              __hip_bfloat16* __restrict__ Hmat,
                                              float* __restrict__ a_l, float* __restrict__ a_r,
                                              int N) {
  const int lane = threadIdx.x & 63;
  const int wid = (blockIdx.x * 256 + threadIdx.x) >> 6;
  if (wid >= N) return;
  const int f32 = flags[0];
  float f = ldv(xin, (size_t)wid * D + lane, f32);
  float n2 = wred_sum(f * f);
  float nrm = fmaxf(sqrtf(n2), EPS_COS);
  fhat[(size_t)wid * D + lane] = __float2bfloat16(f / nrm);
  float Hc = 0.f;
#pragma unroll 8
  for (int k = 0; k < D; ++k) {
    float fk = __shfl(f, k, 64);
    Hc += fk * ldv(W, k * D + lane, f32);
  }
  Hmat[(size_t)wid * D + lane] = __float2bfloat16(Hc);
  float al = wred_sum(Hc * ldv(att, lane, f32));
  float ar = wred_sum(Hc * ldv(att, D + lane, f32));
  if (lane == 0) {
    a_l[wid] = al;
    a_r[wid] = ar;
  }
}

// ---------------- edge kernel: wave per dst node ----------------
__global__ void __launch_bounds__(256) k_edge(const int* __restrict__ row_ptr,
                                              const int* __restrict__ csr_src,
                                              const _Float16* __restrict__ gbuf,
                                              _Float16* __restrict__ lbuf,
                                              _Float16* __restrict__ cbuf,
                                              const __hip_bfloat16* __restrict__ fhat,
                                              const __hip_bfloat16* __restrict__ Hmat,
                                              const float* __restrict__ a_l,
                                              const float* __restrict__ a_r,
                                              const void* __restrict__ beta,
                                              const void* __restrict__ bias,
                                              const void* __restrict__ x,
                                              const void* __restrict__ rW1,
                                              const void* __restrict__ rb1,
                                              const void* __restrict__ rW2,
                                              const void* __restrict__ rb2,
                                              const int* __restrict__ flags,
                                              void* __restrict__ out,
                                              int N, int E, int layer) {
  const int lane = threadIdx.x & 63;
  const int wid = (blockIdx.x * 256 + threadIdx.x) >> 6;
  const bool act = wid < N;
  const int f32 = flags[0];
  const int row = act ? wid : 0;
  int s = 0, e = 0;
  float aln = 0.f;
  if (act) {
    s = min(max(row_ptr[wid], 0), E);
    e = min(max(row_ptr[wid + 1], s), E);
    aln = a_l[wid];
  }
  // fn4: 4 features of fhat[row] per lane (16-lane span; groups duplicate)
  const int g = lane >> 4, sub = lane & 15;
  const ushort4* frow = (const ushort4*)(fhat + (size_t)row * D);
  ushort4 uf = frow[sub];
  float fn0 = b2f(uf.x), fn1 = b2f(uf.y), fn2 = b2f(uf.z), fn3 = b2f(uf.w);

  // phase 1: 4 edges per iter, 16-lane dots; exact segment maxes
  float m1 = -1e30f, m2 = -1e30f;
  for (int base = s; base < e; base += 4) {
    int j = base + g;
    bool ea = j < e;
    int src = ea ? csr_src[j] : 0;
    ushort4 u = ((const ushort4*)(fhat + (size_t)src * D))[sub];
    float d = fn0 * b2f(u.x) + fn1 * b2f(u.y) + fn2 * b2f(u.z) + fn3 * b2f(u.w);
    d += __shfl_xor(d, 1, 64);
    d += __shfl_xor(d, 2, 64);
    d += __shfl_xor(d, 4, 64);
    d += __shfl_xor(d, 8, 64);
    float l = aln + a_r[src];
    l = (l >= 0.f) ? l : NEG_SLOPE * l;
    if (ea) {
      m1 = fmaxf(m1, l);
      m2 = fmaxf(m2, d);
      if (sub == 0) {
        lbuf[j] = (_Float16)l;
        cbuf[j] = (_Float16)d;
      }
    }
  }
  m1 = fmaxf(m1, __shfl_xor(m1, 16, 64));
  m1 = fmaxf(m1, __shfl_xor(m1, 32, 64));
  m2 = fmaxf(m2, __shfl_xor(m2, 16, 64));
  m2 = fmaxf(m2, __shfl_xor(m2, 32, 64));
  __syncthreads();
  // phase 2: softmax denominators (lane-parallel)
  float ps1 = 0.f, ps2 = 0.f;
  for (int j = s + lane; j < e; j += 64) {
    ps1 += __expf((float)lbuf[j] - m1);
    ps2 += __expf((float)cbuf[j] - m2);
  }
  float rs1 = 1.f / (wred_sum(ps1) + EPS_SM);
  float rs2 = 1.f / (wred_sum(ps2) + EPS_SM);
  float bb = 1.f / (1.f + __expf(-ldv(beta, 0, f32)));
  float ob = 1.f - bb;
  // phase 3: per-lane fused weight, broadcast accumulate
  float acc = 0.f, s3 = 0.f;
  for (int base = s; base < e; base += 64) {
    int j = base + lane;
    int cnt = min(64, e - base);
    float p_l = 0.f;
    int srcv = 0;
    if (j < e) {
      srcv = csr_src[j];
      float el = __expf((float)lbuf[j] - m1);
      float ec = __expf((float)cbuf[j] - m2);
      float t = (ob * el * rs1 + bb * ec * rs2) * (float)gbuf[j];
      p_l = __expf(t - 1.f);
    }
    s3 += p_l;
    for (int q = 0; q < cnt; ++q) {
      float p = __shfl(p_l, q, 64);
      int src = __shfl(srcv, q, 64);
      acc += p * __bfloat162float(Hmat[(size_t)src * D + lane]);
    }
  }
  s3 = wred_sum(s3);
  if (act) {
    float v = acc / (s3 + EPS_SM) + ldv(bias, lane, f32);
    v = elu1(v);  // elu inside _cosgat
    if (layer == 0) {
      v = elu1(v);  // inter-layer elu
    } else {
      // fused residual MLP: relu(x@rW1+rb1)@rW2+rb2
      float xv = ldv(x, (size_t)wid * D + lane, f32);
      float a1 = ldv(rb1, lane, f32);
#pragma unroll 8
      for (int k = 0; k < D; ++k) {
        float xk = __shfl(xv, k, 64);
        a1 += xk * ldv(rW1, k * D + lane, f32);
      }
      float tr = fmaxf(a1, 0.f);
      float a2 = ldv(rb2, lane, f32);
#pragma unroll 8
      for (int k = 0; k < D; ++k) {
        float tk = __shfl(tr, k, 64);
        a2 += tk * ldv(rW2, k * D + lane, f32);
      }
      v += a2;
    }
    stv(out, (size_t)wid * D + lane, f32, sane(v));
  }
}

extern "C" void kernel_launch(void* const* d_in, const int* in_sizes, int n_in,
                              void* d_out, int out_size, void* d_ws, size_t ws_size,
                              hipStream_t stream) {
  const void* x = d_in[0];
  const int* ei = (const int*)d_in[1];
  const void* w = d_in[2];
  const void* W0 = d_in[3];
  const void* att0 = d_in[4];
  const void* beta0 = d_in[5];
  const void* b0 = d_in[6];
  const void* W1 = d_in[7];
  const void* att1 = d_in[8];
  const void* beta1 = d_in[9];
  const void* b1 = d_in[10];
  const void* rW1 = d_in[11];
  const void* rb1 = d_in[12];
  const void* rW2 = d_in[13];
  const void* rb2 = d_in[14];

  const int N = in_sizes[0] / D;
  const int E = in_sizes[2];

  char* base = (char*)d_ws;
  size_t off = 0;
  auto alloc = [&](size_t bytes) -> void* {
    void* p = base + off;
    off += (bytes + 255) & ~(size_t)255;
    return p;
  };
  // Total ~27 MB
  int* flags = (int*)alloc(256);
  int* partials = (int*)alloc(1024 * 4);
  int* counts = (int*)alloc((size_t)N * 4);
  int* wptr = (int*)alloc((size_t)N * 4);
  int* row_ptr = (int*)alloc((size_t)(N + 1) * 4);
  int* csr_src = (int*)alloc((size_t)E * 4);
  _Float16* gbuf = (_Float16*)alloc((size_t)E * 2);
  _Float16* cbuf = (_Float16*)alloc((size_t)E * 2);
  _Float16* lbuf = (_Float16*)alloc((size_t)E * 2);
  __hip_bfloat16* fhat = (__hip_bfloat16*)alloc((size_t)N * D * 2);
  __hip_bfloat16* Hmat = (__hip_bfloat16*)alloc((size_t)N * D * 2);
  float* a_l = (float*)alloc((size_t)N * 4);
  float* a_r = (float*)alloc((size_t)N * 4);
  (void)ws_size;

  const int eb = (E + 255) / 256;
  const int nb = (N + 3) / 4;
  const int sb = (N + 255) / 256;  // scan blocks (196)

  hipMemsetAsync(counts, 0, (size_t)N * 4, stream);
  k_detect<<<1, 64, 0, stream>>>((const unsigned short*)x, ei, flags);
  k_count<<<eb, 256, 0, stream>>>(ei, E, N, flags, counts);
  k_scanA<<<sb, 256, 0, stream>>>(counts, row_ptr, partials, N);
  k_scanB<<<1, 1024, 0, stream>>>(partials, row_ptr, sb, N);
  k_scanC<<<sb, 256, 0, stream>>>(row_ptr, wptr, partials, N);
  k_fill<<<eb, 256, 0, stream>>>(ei, w, E, N, flags, wptr, csr_src, gbuf);

  // layer 0: stage elu(elu(.)) into d_out (in detected dtype)
  k_prep<<<nb, 256, 0, stream>>>(x, W0, att0, flags, fhat, Hmat, a_l, a_r, N);
  k_edge<<<nb, 256, 0, stream>>>(row_ptr, csr_src, gbuf, lbuf, cbuf, fhat, Hmat, a_l, a_r,
                                 beta0, b0, x, rW1, rb1, rW2, rb2, flags, d_out, N, E, 0);
  // layer 1: read d_out, overwrite with final = cosgat + residual
  k_prep<<<nb, 256, 0, stream>>>(d_out, W1, att1, flags, fhat, Hmat, a_l, a_r, N);
  k_edge<<<nb, 256, 0, stream>>>(row_ptr, csr_src, gbuf, lbuf, cbuf, fhat, Hmat, a_l, a_r,
                                 beta1, b1, x, rW1, rb1, rW2, rb2, flags, d_out, N, E, 1);
}

// Round 6
// 523.515 us; speedup vs baseline: 2.0945x; 1.3291x over previous
//
#include <hip/hip_runtime.h>
#include <hip/hip_bf16.h>
#include <math.h>

// COSGATEncoder: N=50000, E=1280000, D=64, HEADS=1. f32 in/out (runtime-detected,
// bf16 fallback), edge_index int64 (runtime-detected, int32 fallback).
// R6: latency attack — 8-edge/8-lane gather groups (8x 128B rows in flight),
// wave-private LDS for l/c (no global round trip), register-held p, vectorized
// CSR build, branch-hoisted f32/bf16 loops.

constexpr int D = 64;
constexpr int CAP = 256;  // LDS-resident edges per node; overflow -> global f32 bufs
constexpr float NEG_SLOPE = 0.2f;
constexpr float EPS_COS = 1e-8f;
constexpr float EPS_SM = 1e-16f;

__device__ __forceinline__ float wred_sum(float v) {
#pragma unroll
  for (int off = 32; off > 0; off >>= 1) v += __shfl_xor(v, off, 64);
  return v;
}
__device__ __forceinline__ float elu1(float x) { return x > 0.f ? x : __expf(x) - 1.f; }
__device__ __forceinline__ float sane(float v) {
  return (v == v && fabsf(v) < 1e30f) ? v : 0.f;
}
__device__ __forceinline__ float ldv(const void* p, size_t i, int f32) {
  return f32 ? ((const float*)p)[i]
             : __bfloat162float(((const __hip_bfloat16*)p)[i]);
}
__device__ __forceinline__ void stv(void* p, size_t i, int f32, float v) {
  if (f32) ((float*)p)[i] = v;
  else ((__hip_bfloat16*)p)[i] = __float2bfloat16(v);
}
__device__ __forceinline__ float b2f(unsigned short u) {
  return __uint_as_float(((unsigned int)u) << 16);
}
// unpack 8 bf16 (uint4) -> 8 floats; f[2i]=low half of word i, f[2i+1]=high
__device__ __forceinline__ void unp8(uint4 u, float* f) {
  f[0] = __uint_as_float(u.x << 16);
  f[1] = __uint_as_float(u.x & 0xffff0000u);
  f[2] = __uint_as_float(u.y << 16);
  f[3] = __uint_as_float(u.y & 0xffff0000u);
  f[4] = __uint_as_float(u.z << 16);
  f[5] = __uint_as_float(u.z & 0xffff0000u);
  f[6] = __uint_as_float(u.w << 16);
  f[7] = __uint_as_float(u.w & 0xffff0000u);
}

// flags[0]=1 if x/weights f32; flags[1]=1 if edge_index int64
__global__ void k_detect(const unsigned short* __restrict__ xu,
                         const int* __restrict__ ei, int* __restrict__ flags) {
  const int t = threadIdx.x;  // 64
  float v = b2f(xu[t]);
  float a = fabsf(v);
  unsigned long long m = __ballot(a > 1e-4f && a < 100.f);
  unsigned long long m2 = __ballot(ei[2 * t + 1] != 0);
  if (t == 0) {
    flags[0] = (__popcll(m) >= 60) ? 0 : 1;
    flags[1] = (m2 == 0ull) ? 1 : 0;
  }
}

// ---------------- CSR build (2 edges/thread, vector loads) ----------------
__global__ void k_count(const int* __restrict__ ei, int E, int N,
                        const int* __restrict__ flags, int* __restrict__ counts) {
  int e0 = (blockIdx.x * blockDim.x + threadIdx.x) * 2;
  if (e0 >= E) return;
  const int wide = flags[1];
  int d0, d1;
  const bool has1 = (e0 + 1 < E);
  if (wide) {
    int4 v = *(const int4*)(ei + 2 * (size_t)E + 2 * (size_t)e0);
    d0 = v.x;
    d1 = v.z;
  } else {
    int2 v = *(const int2*)(ei + (size_t)E + e0);
    d0 = v.x;
    d1 = v.y;
  }
  atomicAdd(&counts[min(max(d0, 0), N - 1)], 1);
  if (has1) atomicAdd(&counts[min(max(d1, 0), N - 1)], 1);
}

// 3-pass multiblock exclusive scan
__global__ void k_scanA(const int* __restrict__ counts, int* __restrict__ row_ptr,
                        int* __restrict__ partials, int n) {
  __shared__ int sm[256];
  const int t = threadIdx.x;
  const int i = blockIdx.x * 256 + t;
  int v = (i < n) ? counts[i] : 0;
  sm[t] = v;
  __syncthreads();
  for (int off = 1; off < 256; off <<= 1) {
    int u = (t >= off) ? sm[t - off] : 0;
    __syncthreads();
    sm[t] += u;
    __syncthreads();
  }
  if (i < n) row_ptr[i] = sm[t] - v;
  if (t == 255) partials[blockIdx.x] = sm[255];
}
__global__ void __launch_bounds__(1024) k_scanB(int* __restrict__ partials,
                                                int* __restrict__ row_ptr,
                                                int nb, int n) {
  __shared__ int sm[1024];
  const int t = threadIdx.x;
  int v = (t < nb) ? partials[t] : 0;
  sm[t] = v;
  __syncthreads();
  for (int off = 1; off < 1024; off <<= 1) {
    int u = (t >= off) ? sm[t - off] : 0;
    __syncthreads();
    sm[t] += u;
    __syncthreads();
  }
  if (t < nb) partials[t] = sm[t] - v;
  if (t == nb - 1) row_ptr[n] = sm[t];
}
__global__ void k_scanC(int* __restrict__ row_ptr, int* __restrict__ wptr,
                        const int* __restrict__ partials, int n) {
  const int i = blockIdx.x * 256 + threadIdx.x;
  if (i < n) {
    int r = row_ptr[i] + partials[blockIdx.x];
    row_ptr[i] = r;
    wptr[i] = r;
  }
}

__global__ void k_fill(const int* __restrict__ ei, const void* __restrict__ w,
                       int E, int N, const int* __restrict__ flags,
                       int* __restrict__ wptr, int* __restrict__ csr_src,
                       _Float16* __restrict__ gbuf) {
  int e0 = (blockIdx.x * blockDim.x + threadIdx.x) * 2;
  if (e0 >= E) return;
  const int wide = flags[1], f32 = flags[0];
  const bool has1 = (e0 + 1 < E);
  int s0, s1, d0, d1;
  if (wide) {
    int4 vs = *(const int4*)(ei + 2 * (size_t)e0);
    int4 vd = *(const int4*)(ei + 2 * (size_t)E + 2 * (size_t)e0);
    s0 = vs.x; s1 = vs.z; d0 = vd.x; d1 = vd.z;
  } else {
    int2 vs = *(const int2*)(ei + e0);
    int2 vd = *(const int2*)(ei + (size_t)E + e0);
    s0 = vs.x; s1 = vs.y; d0 = vd.x; d1 = vd.y;
  }
  float w0, w1;
  if (f32) {
    float2 wv = *(const float2*)((const float*)w + e0);
    w0 = wv.x; w1 = wv.y;
  } else {
    const __hip_bfloat16* wb = (const __hip_bfloat16*)w;
    w0 = __bfloat162float(wb[e0]);
    w1 = has1 ? __bfloat162float(wb[e0 + 1]) : 0.f;
  }
  int p0 = atomicAdd(&wptr[min(max(d0, 0), N - 1)], 1);
  p0 = min(max(p0, 0), E - 1);
  csr_src[p0] = min(max(s0, 0), N - 1);
  gbuf[p0] = (_Float16)fminf(fmaxf(1.f - 0.25f * fminf(w0, 4.f), 0.f), 1.f);
  if (has1) {
    int p1 = atomicAdd(&wptr[min(max(d1, 0), N - 1)], 1);
    p1 = min(max(p1, 0), E - 1);
    csr_src[p1] = min(max(s1, 0), N - 1);
    gbuf[p1] = (_Float16)fminf(fmaxf(1.f - 0.25f * fminf(w1, 4.f), 0.f), 1.f);
  }
}

// ---------------- per-layer node prep ----------------
__global__ void __launch_bounds__(256) k_prep(const void* __restrict__ xin,
                                              const void* __restrict__ W,
                                              const void* __restrict__ att,
                                              const int* __restrict__ flags,
                                              __hip_bfloat16* __restrict__ fhat,
                                              __hip_bfloat16* __restrict__ Hmat,
                                              float* __restrict__ a_l, float* __restrict__ a_r,
                                              int N) {
  const int lane = threadIdx.x & 63;
  const int wid = (blockIdx.x * 256 + threadIdx.x) >> 6;
  if (wid >= N) return;
  const int f32 = flags[0];
  float f, Hc = 0.f;
  if (f32) {
    const float* xf = (const float*)xin;
    const float* Wf = (const float*)W;
    f = xf[(size_t)wid * D + lane];
#pragma unroll 8
    for (int k = 0; k < D; ++k) Hc += __shfl(f, k, 64) * Wf[k * D + lane];
  } else {
    const __hip_bfloat16* xb = (const __hip_bfloat16*)xin;
    const __hip_bfloat16* Wb = (const __hip_bfloat16*)W;
    f = __bfloat162float(xb[(size_t)wid * D + lane]);
#pragma unroll 8
    for (int k = 0; k < D; ++k) Hc += __shfl(f, k, 64) * __bfloat162float(Wb[k * D + lane]);
  }
  float n2 = wred_sum(f * f);
  float nrm = fmaxf(sqrtf(n2), EPS_COS);
  fhat[(size_t)wid * D + lane] = __float2bfloat16(f / nrm);
  Hmat[(size_t)wid * D + lane] = __float2bfloat16(Hc);
  float al = wred_sum(Hc * ldv(att, lane, f32));
  float ar = wred_sum(Hc * ldv(att, D + lane, f32));
  if (lane == 0) {
    a_l[wid] = al;
    a_r[wid] = ar;
  }
}

// ---------------- edge kernel: wave per dst node, 8-edge/8-lane groups ----------------
__global__ void __launch_bounds__(256) k_edge(const int* __restrict__ row_ptr,
                                              const int* __restrict__ csr_src,
                                              _Float16* __restrict__ gbuf,
                                              float* __restrict__ lbuf,
                                              float* __restrict__ cbuf,
                                              const __hip_bfloat16* __restrict__ fhat,
                                              const __hip_bfloat16* __restrict__ Hmat,
                                              const float* __restrict__ a_l,
                                              const float* __restrict__ a_r,
                                              const void* __restrict__ beta,
                                              const void* __restrict__ bias,
                                              const void* __restrict__ x,
                                              const void* __restrict__ rW1,
                                              const void* __restrict__ rb1,
                                              const void* __restrict__ rW2,
                                              const void* __restrict__ rb2,
                                              const int* __restrict__ flags,
                                              void* __restrict__ out,
                                              int N, int E, int layer) {
  const int lane = threadIdx.x & 63;
  const int wv = threadIdx.x >> 6;  // wave in block (0..3)
  const int wid = blockIdx.x * 4 + wv;
  // wave-private LDS: l/c for up to CAP edges + 64-float transpose buffer
  __shared__ float2 lds_lc[4][CAP];
  __shared__ float lds_t[4][D];
  if (wid >= N) return;
  const int f32 = flags[0];
  const int g = lane >> 3;   // edge slot in 8-edge group
  const int sub = lane & 7;  // feature block: features [8*sub, 8*sub+8)
  const int s = min(max(row_ptr[wid], 0), E);
  const int e = min(max(row_ptr[wid + 1], s), E);
  const int deg = e - s;
  const float aln = a_l[wid];
  float2* lc = lds_lc[wv];

  // dst fhat features for this lane (8 bf16)
  float fn[8];
  unp8(((const uint4*)(fhat + (size_t)wid * D))[sub], fn);

  // ---- phase 1: 8 edges/iter; dot via 8-lane groups; exact maxes; l/c -> LDS ----
  float m1 = -1e30f, m2 = -1e30f;
#pragma unroll 2
  for (int base = 0; base < deg; base += 8) {
    const int j = base + g;
    const bool val = j < deg;
    const int src = val ? csr_src[s + j] : wid;
    float hv[8];
    unp8(((const uint4*)(fhat + (size_t)src * D))[sub], hv);
    float d = 0.f;
#pragma unroll
    for (int i = 0; i < 8; ++i) d += fn[i] * hv[i];
    d += __shfl_xor(d, 1, 64);
    d += __shfl_xor(d, 2, 64);
    d += __shfl_xor(d, 4, 64);
    float l = aln + a_r[src];
    l = (l >= 0.f) ? l : NEG_SLOPE * l;
    if (val) {
      m1 = fmaxf(m1, l);
      m2 = fmaxf(m2, d);
      if (sub == 0) {
        if (j < CAP) lc[j] = make_float2(l, d);
        else {
          lbuf[s + j] = l;
          cbuf[s + j] = d;
        }
      }
    }
  }
  m1 = fmaxf(m1, __shfl_xor(m1, 8, 64));
  m1 = fmaxf(m1, __shfl_xor(m1, 16, 64));
  m1 = fmaxf(m1, __shfl_xor(m1, 32, 64));
  m2 = fmaxf(m2, __shfl_xor(m2, 8, 64));
  m2 = fmaxf(m2, __shfl_xor(m2, 16, 64));
  m2 = fmaxf(m2, __shfl_xor(m2, 32, 64));

  // ---- phase 2: softmax denominators (lane-parallel over edges) ----
  float ps1 = 0.f, ps2 = 0.f;
  for (int j = lane; j < deg; j += 64) {
    float lx, cx;
    if (j < CAP) {
      float2 t = lc[j];
      lx = t.x;
      cx = t.y;
    } else {
      lx = lbuf[s + j];
      cx = cbuf[s + j];
    }
    ps1 += __expf(lx - m1);
    ps2 += __expf(cx - m2);
  }
  const float rs1 = 1.f / (wred_sum(ps1) + EPS_SM);
  const float rs2 = 1.f / (wred_sum(ps2) + EPS_SM);
  const float bb = 1.f / (1.f + __expf(-ldv(beta, 0, f32)));
  const float ob = 1.f - bb;

  // ---- phase 3 pre-pass: per-edge fused weight p (regs for chunks 0..3) ----
  float sp = 0.f;
  float p0 = 0.f, p1 = 0.f, p2 = 0.f, p3 = 0.f;
  int q0 = 0, q1 = 0, q2 = 0, q3 = 0;
  auto prep_chunk = [&](int c, float& pc, int& qc) {
    const int j = c * 64 + lane;
    if (j < deg) {
      float2 t = lc[j];  // chunks 0..3 are always < CAP
      float el = __expf(t.x - m1);
      float ec = __expf(t.y - m2);
      float tt = (ob * el * rs1 + bb * ec * rs2) * (float)gbuf[s + j];
      pc = __expf(tt - 1.f);
      qc = csr_src[s + j];
      sp += pc;
    }
  };
  prep_chunk(0, p0, q0);
  if (deg > 64) prep_chunk(1, p1, q1);
  if (deg > 128) prep_chunk(2, p2, q2);
  if (deg > 192) prep_chunk(3, p3, q3);
  // overflow chunks: p -> gbuf (gbuf consumed above; safe to overwrite)
  for (int c = 4; c * 64 < deg; ++c) {
    const int j = c * 64 + lane;
    if (j < deg) {
      float lx = lbuf[s + j], cx = cbuf[s + j];
      float el = __expf(lx - m1);
      float ec = __expf(cx - m2);
      float tt = (ob * el * rs1 + bb * ec * rs2) * (float)gbuf[s + j];
      float p = __expf(tt - 1.f);
      gbuf[s + j] = (_Float16)p;
      sp += p;
    }
  }
  const float s3 = wred_sum(sp);
  const float rinv = 1.f / (s3 + EPS_SM);

  // ---- phase 3 accumulate: 8 edges/iter, acc[8] per lane ----
  float acc[8] = {0.f, 0.f, 0.f, 0.f, 0.f, 0.f, 0.f, 0.f};
  auto accum_reg = [&](float pc, int qc, int cbase) {
    const int clim = min(64, deg - cbase);
#pragma unroll 2
    for (int b8 = 0; b8 < clim; b8 += 8) {
      const float p = __shfl(pc, b8 + g, 64);  // p==0 for slots past deg
      const int src = __shfl(qc, b8 + g, 64);
      float hv[8];
      unp8(((const uint4*)(Hmat + (size_t)src * D))[sub], hv);
#pragma unroll
      for (int i = 0; i < 8; ++i) acc[i] += p * hv[i];
    }
  };
  accum_reg(p0, q0, 0);
  if (deg > 64) accum_reg(p1, q1, 64);
  if (deg > 128) accum_reg(p2, q2, 128);
  if (deg > 192) accum_reg(p3, q3, 192);
  for (int c = 4; c * 64 < deg; ++c) {
    const int cbase = c * 64;
    const int clim = min(64, deg - cbase);
    for (int b8 = 0; b8 < clim; b8 += 8) {
      const int j = cbase + b8 + g;
      const float p = (j < deg) ? (float)gbuf[s + j] : 0.f;
      const int src = (j < deg) ? csr_src[s + j] : 0;
      float hv[8];
      unp8(((const uint4*)(Hmat + (size_t)src * D))[sub], hv);
#pragma unroll
      for (int i = 0; i < 8; ++i) acc[i] += p * hv[i];
    }
  }
  // reduce across the 8 groups
#pragma unroll
  for (int i = 0; i < 8; ++i) {
    acc[i] += __shfl_xor(acc[i], 8, 64);
    acc[i] += __shfl_xor(acc[i], 16, 64);
    acc[i] += __shfl_xor(acc[i], 32, 64);
  }
  // transpose to lane=feature layout via wave-private LDS
  if (g == 0) {
#pragma unroll
    for (int i = 0; i < 8; ++i) lds_t[wv][8 * sub + i] = acc[i];
  }
  float v = lds_t[wv][lane] * rinv + ldv(bias, lane, f32);
  v = elu1(v);  // elu inside _cosgat
  if (layer == 0) {
    v = elu1(v);  // inter-layer elu
  } else {
    // fused residual MLP: relu(x@rW1+rb1)@rW2+rb2
    float xv = ldv(x, (size_t)wid * D + lane, f32);
    float a1 = ldv(rb1, lane, f32);
    float a2;
    if (f32) {
      const float* w1 = (const float*)rW1;
      const float* w2 = (const float*)rW2;
#pragma unroll 8
      for (int k = 0; k < D; ++k) a1 += __shfl(xv, k, 64) * w1[k * D + lane];
      float tr = fmaxf(a1, 0.f);
      a2 = ((const float*)rb2)[lane];
#pragma unroll 8
      for (int k = 0; k < D; ++k) a2 += __shfl(tr, k, 64) * w2[k * D + lane];
    } else {
      const __hip_bfloat16* w1 = (const __hip_bfloat16*)rW1;
      const __hip_bfloat16* w2 = (const __hip_bfloat16*)rW2;
#pragma unroll 8
      for (int k = 0; k < D; ++k) a1 += __shfl(xv, k, 64) * __bfloat162float(w1[k * D + lane]);
      float tr = fmaxf(a1, 0.f);
      a2 = __bfloat162float(((const __hip_bfloat16*)rb2)[lane]);
#pragma unroll 8
      for (int k = 0; k < D; ++k) a2 += __shfl(tr, k, 64) * __bfloat162float(w2[k * D + lane]);
    }
    v += a2;
  }
  stv(out, (size_t)wid * D + lane, f32, sane(v));
}

extern "C" void kernel_launch(void* const* d_in, const int* in_sizes, int n_in,
                              void* d_out, int out_size, void* d_ws, size_t ws_size,
                              hipStream_t stream) {
  const void* x = d_in[0];
  const int* ei = (const int*)d_in[1];
  const void* w = d_in[2];
  const void* W0 = d_in[3];
  const void* att0 = d_in[4];
  const void* beta0 = d_in[5];
  const void* b0 = d_in[6];
  const void* W1 = d_in[7];
  const void* att1 = d_in[8];
  const void* beta1 = d_in[9];
  const void* b1 = d_in[10];
  const void* rW1 = d_in[11];
  const void* rb1 = d_in[12];
  const void* rW2 = d_in[13];
  const void* rb2 = d_in[14];

  const int N = in_sizes[0] / D;
  const int E = in_sizes[2];

  char* base = (char*)d_ws;
  size_t off = 0;
  auto alloc = [&](size_t bytes) -> void* {
    void* p = base + off;
    off += (bytes + 255) & ~(size_t)255;
    return p;
  };
  // Total ~31.7 MB
  int* flags = (int*)alloc(256);
  int* partials = (int*)alloc(1024 * 4);
  int* counts = (int*)alloc((size_t)N * 4);
  int* wptr = (int*)alloc((size_t)N * 4);
  int* row_ptr = (int*)alloc((size_t)(N + 1) * 4);
  int* csr_src = (int*)alloc((size_t)E * 4);
  _Float16* gbuf = (_Float16*)alloc((size_t)E * 2);
  float* lbuf = (float*)alloc((size_t)E * 4);
  float* cbuf = (float*)alloc((size_t)E * 4);
  __hip_bfloat16* fhat = (__hip_bfloat16*)alloc((size_t)N * D * 2);
  __hip_bfloat16* Hmat = (__hip_bfloat16*)alloc((size_t)N * D * 2);
  float* a_l = (float*)alloc((size_t)N * 4);
  float* a_r = (float*)alloc((size_t)N * 4);
  (void)ws_size;

  const int eb2 = (E / 2 + 255) / 256;
  const int nb = (N + 3) / 4;
  const int sb = (N + 255) / 256;

  hipMemsetAsync(counts, 0, (size_t)N * 4, stream);
  k_detect<<<1, 64, 0, stream>>>((const unsigned short*)x, ei, flags);
  k_count<<<eb2, 256, 0, stream>>>(ei, E, N, flags, counts);
  k_scanA<<<sb, 256, 0, stream>>>(counts, row_ptr, partials, N);
  k_scanB<<<1, 1024, 0, stream>>>(partials, row_ptr, sb, N);
  k_scanC<<<sb, 256, 0, stream>>>(row_ptr, wptr, partials, N);
  k_fill<<<eb2, 256, 0, stream>>>(ei, w, E, N, flags, wptr, csr_src, gbuf);

  // layer 0: stage elu(elu(.)) into d_out (in detected dtype)
  k_prep<<<nb, 256, 0, stream>>>(x, W0, att0, flags, fhat, Hmat, a_l, a_r, N);
  k_edge<<<nb, 256, 0, stream>>>(row_ptr, csr_src, gbuf, lbuf, cbuf, fhat, Hmat, a_l, a_r,
                                 beta0, b0, x, rW1, rb1, rW2, rb2, flags, d_out, N, E, 0);
  // layer 1: read d_out, overwrite with final = cosgat + residual
  k_prep<<<nb, 256, 0, stream>>>(d_out, W1, att1, flags, fhat, Hmat, a_l, a_r, N);
  k_edge<<<nb, 256, 0, stream>>>(row_ptr, csr_src, gbuf, lbuf, cbuf, fhat, Hmat, a_l, a_r,
                                 beta1, b1, x, rW1, rb1, rW2, rb2, flags, d_out, N, E, 1);
}